// Round 13
// baseline (864.198 us; speedup 1.0000x reference)
//
#include <hip/hip_runtime.h>

#define T_   2
#define IN_  6
#define DIM_ 36
#define LIN_ 54
#define OUT_ 18
#define BN_EPS 1e-5f

#define WSH_   7        // bucket width = 128 dst nodes
#define WMSK_  127
#define CAP_   2560     // per-bucket capacity (mean 2046, 11 sigma headroom)
#define TILE_  12288    // edges per binsort block
#define NBMAX_ 1024     // max buckets supported by in-LDS scan

__device__ __forceinline__ unsigned short f2bf(float f) {
    unsigned u = __float_as_uint(f);
    unsigned r = (u + 0x7FFFu + ((u >> 16) & 1u)) >> 16;    // RNE
    return (unsigned short)r;
}
__device__ __forceinline__ float bf2f(unsigned short h) {
    return __uint_as_float(((unsigned)h) << 16);
}
__device__ __forceinline__ unsigned packbf(float a, float b) {
    return (unsigned)f2bf(a) | ((unsigned)f2bf(b) << 16);
}

// ===========================================================================
// binsort_k: bin edges by dst bucket with LDS staging; coalesced packed
// writes (src 17b | dstoff 7b). 16-lane sub-groups in copy-out (R12).
// ===========================================================================
__global__ __launch_bounds__(256) void binsort_k(
    const int* __restrict__ ei, int t0, int gbin,
    int* __restrict__ bcnt, int* __restrict__ bbuf, int ne, int nb)
{
    __shared__ int cntl[NBMAX_], cursl[NBMAX_], gbasel[NBMAX_];
    __shared__ int aux[256];
    __shared__ int sortedl[TILE_];

    const int tid  = threadIdx.x;
    const int lt   = blockIdx.x / gbin;
    const int tile = blockIdx.x % gbin;
    const int base = tile * TILE_;
    const int cnt_e = min(TILE_, ne - base);
    const int* srcp = ei + (size_t)(t0 + lt) * 2 * ne;
    const int* dstp = srcp + ne;
    int* bcnt_t = bcnt + (size_t)lt * nb;

    for (int i = tid; i < NBMAX_; i += 256) cntl[i] = 0;
    __syncthreads();

    for (int i = tid; i < cnt_e; i += 256)
        atomicAdd(&cntl[dstp[base + i] >> WSH_], 1);
    __syncthreads();

    int t4 = tid * 4;
    int c0 = cntl[t4+0], c1 = cntl[t4+1], c2 = cntl[t4+2], c3 = cntl[t4+3];
    int lsum = c0 + c1 + c2 + c3;
    aux[tid] = lsum;
    __syncthreads();
    for (int off = 1; off < 256; off <<= 1) {
        int v = (tid >= off) ? aux[tid - off] : 0;
        __syncthreads();
        aux[tid] += v;
        __syncthreads();
    }
    int eb = aux[tid] - lsum;
    cursl[t4+0] = eb;
    cursl[t4+1] = eb + c0;
    cursl[t4+2] = eb + c0 + c1;
    cursl[t4+3] = eb + c0 + c1 + c2;
    __syncthreads();

    for (int b = tid; b < nb; b += 256) {
        int c = cntl[b];
        gbasel[b] = c ? atomicAdd(&bcnt_t[b], c) : 0;
    }
    __syncthreads();

    for (int i = tid; i < cnt_e; i += 256) {
        int s = srcp[base + i], d = dstp[base + i];
        int p = atomicAdd(&cursl[d >> WSH_], 1);
        sortedl[p] = s | ((d & WMSK_) << 17);
    }
    __syncthreads();

    int grp16 = tid >> 4, ln16 = tid & 15;
    for (int b = grp16; b < nb; b += 16) {
        int c = cntl[b];
        if (!c) continue;
        int lb = cursl[b] - c;
        int gb = gbasel[b];
        size_t ga = ((size_t)lt * nb + b) * CAP_ + gb;
        for (int i = ln16; i < c; i += 16)
            if (gb + i < CAP_) bbuf[ga + i] = sortedl[lb + i];
    }
}

// ===========================================================================
// csrify_k: one block per (t,bucket): sort bucket by dst node in LDS, write
// back coalesced (unpacked src), emit rp (global into bbuf) and deg.
// ===========================================================================
__global__ __launch_bounds__(256) void csrify_k(
    const int* __restrict__ bcnt, int* __restrict__ bbuf,
    int* __restrict__ rp, int* __restrict__ deg, int n, int nb)
{
    __shared__ int ent[CAP_], srt[CAP_];
    __shared__ int cnt[128], cur[128], sc[128];
    const int b = blockIdx.x, tid = threadIdx.x;
    const int blocal = b % nb, lt = b / nb;
    int c = min(bcnt[b], CAP_);
    int* seg = bbuf + (size_t)b * CAP_;

    for (int i = tid; i < c; i += 256) ent[i] = seg[i];
    if (tid < 128) cnt[tid] = 0;
    __syncthreads();
    for (int i = tid; i < c; i += 256)
        atomicAdd(&cnt[(ent[i] >> 17) & WMSK_], 1);
    __syncthreads();
    if (tid < 128) sc[tid] = cnt[tid];
    __syncthreads();
    for (int off = 1; off < 128; off <<= 1) {
        int v = (tid >= off && tid < 128) ? sc[tid - off] : 0;
        __syncthreads();
        if (tid < 128) sc[tid] += v;
        __syncthreads();
    }
    int node0 = blocal << WSH_;
    if (tid < 128) {
        int excl = sc[tid] - cnt[tid];
        cur[tid] = excl;
        if (node0 + tid < n) {
            rp[(size_t)lt * n + node0 + tid]  = b * CAP_ + excl;
            deg[(size_t)lt * n + node0 + tid] = cnt[tid];
        }
    }
    __syncthreads();
    for (int i = tid; i < c; i += 256) {
        int v = ent[i];
        int p = atomicAdd(&cur[(v >> 17) & WMSK_], 1);
        srt[p] = v & 0x1FFFF;
    }
    __syncthreads();
    for (int i = tid; i < c; i += 256) seg[i] = srt[i];
}

// ===========================================================================
// gather_k (conv1, D=6, fp32): agg[i] = x[i] + sum_{nbr} x[nbr].
// ===========================================================================
template<int D>
__global__ __launch_bounds__(576) void gather_k(
        const float* __restrict__ hbase, size_t hstride,
        const int* __restrict__ rp, const int* __restrict__ deg,
        const int* __restrict__ csr, float* __restrict__ agg,
        size_t astride, int n)
{
    const int NPB = 576 / D;
    const int slot = blockIdx.y;
    const float* h = hbase + (size_t)slot * hstride;
    int g = blockIdx.x * NPB + threadIdx.x / D;
    int lane = threadIdx.x % D;
    if (g >= n) return;
    int lo = rp[(size_t)slot * n + g], hi = lo + deg[(size_t)slot * n + g];
    float a0 = h[(size_t)g * D + lane], a1 = 0.f, a2 = 0.f, a3 = 0.f;
    int e = lo;
    for (; e + 3 < hi; e += 4) {
        int s0 = csr[e], s1 = csr[e + 1], s2 = csr[e + 2], s3 = csr[e + 3];
        a0 += h[(size_t)s0 * D + lane];
        a1 += h[(size_t)s1 * D + lane];
        a2 += h[(size_t)s2 * D + lane];
        a3 += h[(size_t)s3 * D + lane];
    }
    for (; e < hi; ++e) a0 += h[(size_t)csr[e] * D + lane];
    agg[(size_t)slot * astride + (size_t)g * D + lane] = (a0 + a1) + (a2 + a3);
}

// ===========================================================================
// gather36h_k: bf16 rows, 9 lanes/node (4 features/lane via uint2 = 8B/lane).
// agg[i] = self + sum_nbr, fp32 out. Barrier-free, register accumulation.
// (Triple-confirmed R5/R9/R11: must NOT be fused with the MLP.)
// ===========================================================================
__global__ __launch_bounds__(576) void gather36h_k(
        const unsigned short* __restrict__ zh, size_t zhstride,
        const int* __restrict__ rp, const int* __restrict__ deg,
        const int* __restrict__ csr, float* __restrict__ agg,
        size_t astride, int n)
{
    const int slot = blockIdx.y;
    const unsigned short* zhs = zh + (size_t)slot * zhstride;
    int g = blockIdx.x * 64 + threadIdx.x / 9;
    int lane = threadIdx.x % 9;
    if (g >= n) return;
    size_t off = (size_t)slot * n + g;
    int lo = rp[off], hi = lo + deg[off];

    uint2 v = *reinterpret_cast<const uint2*>(zhs + (size_t)g * DIM_ + 4 * lane);
    float a0 = bf2f((unsigned short)(v.x & 0xffff));
    float a1 = bf2f((unsigned short)(v.x >> 16));
    float a2 = bf2f((unsigned short)(v.y & 0xffff));
    float a3 = bf2f((unsigned short)(v.y >> 16));
    float b0 = 0.f, b1 = 0.f, b2 = 0.f, b3 = 0.f;

    int e = lo;
    for (; e + 1 < hi; e += 2) {
        int s0 = csr[e], s1 = csr[e + 1];
        uint2 u0 = *reinterpret_cast<const uint2*>(zhs + (size_t)s0 * DIM_ + 4 * lane);
        uint2 u1 = *reinterpret_cast<const uint2*>(zhs + (size_t)s1 * DIM_ + 4 * lane);
        a0 += bf2f((unsigned short)(u0.x & 0xffff));
        a1 += bf2f((unsigned short)(u0.x >> 16));
        a2 += bf2f((unsigned short)(u0.y & 0xffff));
        a3 += bf2f((unsigned short)(u0.y >> 16));
        b0 += bf2f((unsigned short)(u1.x & 0xffff));
        b1 += bf2f((unsigned short)(u1.x >> 16));
        b2 += bf2f((unsigned short)(u1.y & 0xffff));
        b3 += bf2f((unsigned short)(u1.y >> 16));
    }
    if (e < hi) {
        uint2 u0 = *reinterpret_cast<const uint2*>(zhs + (size_t)csr[e] * DIM_ + 4 * lane);
        a0 += bf2f((unsigned short)(u0.x & 0xffff));
        a1 += bf2f((unsigned short)(u0.x >> 16));
        a2 += bf2f((unsigned short)(u0.y & 0xffff));
        a3 += bf2f((unsigned short)(u0.y >> 16));
    }
    float4 r; r.x = a0 + b0; r.y = a1 + b1; r.z = a2 + b2; r.w = a3 + b3;
    *reinterpret_cast<float4*>(agg + (size_t)slot * astride + (size_t)g * DIM_ + 4 * lane) = r;
}

// ===========================================================================
// node_q: node MLP with 4 LANES PER NODE (R12's 1-thread/node was wave-
// starved: 12 waves/CU, VALUBusy 23%). 256 thr = 64 nodes. Each lane loads
// the full hin row (4-lane same-addr -> L1 broadcast, aligned float4),
// computes 9 FULL rows of layer A (no reduction), exchanges y via 36 shfl
// within its 4-lane group, computes 9 full rows of layer B. 4x waves, 4x
// shorter critical path, aligned vector weight loads.
// ===========================================================================
template<int DIN, bool AFF>
__global__ __launch_bounds__(256) void node_q(
    const float* __restrict__ agg, size_t astride,
    const int* __restrict__ deg,
    const float* __restrict__ coef,
    const float* __restrict__ wAb, const float* __restrict__ bAb,
    const float* __restrict__ wBb, const float* __restrict__ bBb,
    int t0,
    unsigned short* __restrict__ zho, size_t zstride,
    float* __restrict__ bstats, int gn, int n)
{
    __shared__ float sstat[4][2 * DIM_];
    const int slot = blockIdx.y;
    const int t = t0 + slot;
    const float* wa = wAb + (size_t)t * DIM_ * DIN;
    const float* ba = bAb + (size_t)t * DIM_;
    const float* wb = wBb + (size_t)t * DIM_ * DIM_;
    const float* bb = bBb + (size_t)t * DIM_;

    const int tid = threadIdx.x;
    const int grp = tid >> 2, p = tid & 3;
    int node = blockIdx.x * 64 + grp;
    bool act = node < n;

    // full hin per lane (4x redundant, same-address broadcast from L1)
    float hin[DIN];
    if (act) {
        const float* ar = agg + (size_t)slot * astride + (size_t)node * DIN;
        if constexpr (DIN == 36) {
            const float4* ar4 = reinterpret_cast<const float4*>(ar);
            #pragma unroll
            for (int q = 0; q < 9; ++q) {
                float4 av = ar4[q];
                hin[4*q+0] = av.x; hin[4*q+1] = av.y;
                hin[4*q+2] = av.z; hin[4*q+3] = av.w;
            }
        } else {
            const float2* ar2 = reinterpret_cast<const float2*>(ar);
            #pragma unroll
            for (int q = 0; q < DIN / 2; ++q) {
                float2 av = ar2[q];
                hin[2*q+0] = av.x; hin[2*q+1] = av.y;
            }
        }
        if constexpr (AFF) {
            const float* ca  = coef + (size_t)slot * 2 * DIM_;
            const float* cb2 = ca + DIM_;
            float ds = 1.0f + (float)deg[(size_t)slot * n + node];
            #pragma unroll
            for (int k = 0; k < DIN; ++k)
                hin[k] = ca[k] * hin[k] + ds * cb2[k];
        }
    } else {
        #pragma unroll
        for (int k = 0; k < DIN; ++k) hin[k] = 0.f;
    }

    // layer A: this lane's 9 full rows (j = 9p..9p+8)
    float yp[9];
    #pragma unroll
    for (int r = 0; r < 9; ++r) {
        int j = 9 * p + r;
        float acc = ba[j];
        #pragma unroll
        for (int k = 0; k < DIN; ++k) acc = fmaf(wa[j * DIN + k], hin[k], acc);
        yp[r] = fmaxf(acc, 0.f);
    }

    // exchange y across the 4-lane group -> full y[36]
    float yf[DIM_];
    int base = tid & ~3;
    #pragma unroll
    for (int m = 0; m < 4; ++m) {
        #pragma unroll
        for (int r = 0; r < 9; ++r)
            yf[9 * m + r] = __shfl(yp[r], base + m);
    }

    // layer B: this lane's 9 full rows
    float op[9];
    #pragma unroll
    for (int r = 0; r < 9; ++r) {
        int j = 9 * p + r;
        float acc = bb[j];
        #pragma unroll
        for (int k = 0; k < DIM_; ++k) acc = fmaf(wb[j * DIM_ + k], yf[k], acc);
        op[r] = act ? fmaxf(acc, 0.f) : 0.f;
    }

    if (act) {
        unsigned short* zr = zho + (size_t)slot * zstride + (size_t)node * DIM_ + 9 * p;
        #pragma unroll
        for (int r = 0; r < 9; ++r) zr[r] = f2bf(op[r]);
    }

    // BN stats: feature f=9p+r is at reg r of lanes == p (mod 4).
    // Reduce over the 16 groups of the wave (offs 32,16,8,4), lanes<4 own
    // wave partials; cross-wave via LDS.
    int wid = tid >> 6, lane = tid & 63;
    float ss[9], sq[9];
    #pragma unroll
    for (int r = 0; r < 9; ++r) { ss[r] = op[r]; sq[r] = op[r] * op[r]; }
    #pragma unroll
    for (int r = 0; r < 9; ++r) {
        for (int off = 32; off >= 4; off >>= 1) {
            ss[r] += __shfl_down(ss[r], off);
            sq[r] += __shfl_down(sq[r], off);
        }
    }
    if (lane < 4) {
        #pragma unroll
        for (int r = 0; r < 9; ++r) {
            sstat[wid][9 * lane + r]        = ss[r];
            sstat[wid][DIM_ + 9 * lane + r] = sq[r];
        }
    }
    __syncthreads();
    if (tid < 2 * DIM_) {
        float s = sstat[0][tid] + sstat[1][tid] + sstat[2][tid] + sstat[3][tid];
        bstats[((size_t)slot * gn + blockIdx.x) * (2 * DIM_) + tid] = s;
    }
}

// ===========================================================================
// bnfin_k: reduce nrows stat rows -> fused affine coef {a, b2}. Grid (tc).
// ===========================================================================
__global__ __launch_bounds__(288) void bnfin_k(
    const float* __restrict__ bstats, int nrows, int rstride,
    const float* __restrict__ bng, const float* __restrict__ bnb,
    int t0, int c, float* __restrict__ coef, float inv_n)
{
    __shared__ float part[4][2 * DIM_];
    const int slot = blockIdx.x;
    const int t = t0 + slot;
    int tid = threadIdx.x;
    int col = tid % (2 * DIM_), quarter = tid / (2 * DIM_);
    const float* bs = bstats + (size_t)slot * rstride * (2 * DIM_);
    float s = 0.f;
    for (int i = quarter; i < nrows; i += 4) s += bs[(size_t)i * (2 * DIM_) + col];
    part[quarter][col] = s;
    __syncthreads();
    if (tid < 2 * DIM_)
        part[0][tid] = part[0][tid] + part[1][tid] + part[2][tid] + part[3][tid];
    __syncthreads();
    if (tid < DIM_) {
        float mean = part[0][tid] * inv_n;
        float var  = part[0][DIM_ + tid] * inv_n - mean * mean;
        float aa   = bng[((size_t)t * 3 + c) * DIM_ + tid] / sqrtf(var + BN_EPS);
        coef[(size_t)slot * 2 * DIM_ + tid]        = aa;
        coef[(size_t)slot * 2 * DIM_ + DIM_ + tid] = bnb[((size_t)t * 3 + c) * DIM_ + tid] - aa * mean;
    }
}

// ===========================================================================
// pool_k: per-graph mean pool over bf16 z (batch sorted), conv-3 coef.
// ===========================================================================
__global__ __launch_bounds__(288) void pool_k(
    const unsigned short* __restrict__ zh, size_t zstride,
    const float* __restrict__ coef,
    const int* __restrict__ batch, int t0,
    float* __restrict__ emb, int n)
{
    __shared__ int slo, shi;
    __shared__ float sp0[16][19], sp1[16][19];
    const int slot = blockIdx.y;
    const int t = t0 + slot;
    const int* bt = batch + (size_t)t * n;
    const unsigned short* zt = zh + (size_t)slot * zstride;
    const float* ca  = coef + (size_t)slot * 2 * DIM_;
    const float* cb2 = ca + DIM_;

    int g = blockIdx.x;
    int tid = threadIdx.x;
    if (tid == 0) {
        int lo = 0, hi = n;
        while (lo < hi) { int m = (lo + hi) >> 1; if (bt[m] < g) lo = m + 1; else hi = m; }
        slo = lo;
        int lo2 = lo, hi2 = n;
        while (lo2 < hi2) { int m = (lo2 + hi2) >> 1; if (bt[m] < g + 1) lo2 = m + 1; else hi2 = m; }
        shi = lo2;
    }
    __syncthreads();
    int lo = slo, hi = shi;
    int fp = tid % 18, j = tid / 18;
    float acc0 = 0.f, acc1 = 0.f;
    for (int i = lo + j; i < hi; i += 16) {
        unsigned v = *reinterpret_cast<const unsigned*>(zt + (size_t)i * DIM_ + 2 * fp);
        acc0 += bf2f((unsigned short)(v & 0xffff));
        acc1 += bf2f((unsigned short)(v >> 16));
    }
    sp0[j][fp] = acc0;
    sp1[j][fp] = acc1;
    __syncthreads();
    if (tid < DIM_) {
        int f = tid, fpair = f >> 1, hi_ = f & 1;
        float s = 0.f;
        #pragma unroll
        for (int jj = 0; jj < 16; ++jj)
            s += hi_ ? sp1[jj][fpair] : sp0[jj][fpair];
        int cnt = hi - lo;
        float val = 0.f;
        if (cnt > 0) val = ca[f] * (s / (float)cnt) + cb2[f];
        emb[(size_t)g * (T_ * DIM_) + t * DIM_ + f] = val;
    }
}

// ===========================================================================
// head_k: one 64-thread block per graph, layers staged through LDS.
// ===========================================================================
__global__ __launch_bounds__(64) void head_k(
    const float* __restrict__ emb,
    const float* __restrict__ hw1, const float* __restrict__ hb1,
    const float* __restrict__ hw2, const float* __restrict__ hb2,
    const float* __restrict__ hw3, const float* __restrict__ hb3,
    float* __restrict__ out, int ng)
{
    const int EMB = T_ * DIM_;
    int g = blockIdx.x;
    if (g >= ng) return;
    __shared__ float se[EMB], st1[LIN_], st2[OUT_];
    int tid = threadIdx.x;
    for (int i = tid; i < EMB; i += 64) se[i] = emb[(size_t)g * EMB + i];
    __syncthreads();
    if (tid < LIN_) {
        float acc = hb1[tid];
        #pragma unroll
        for (int k = 0; k < EMB; ++k) acc = fmaf(hw1[tid * EMB + k], se[k], acc);
        st1[tid] = fmaxf(acc, 0.f);
    }
    __syncthreads();
    if (tid < OUT_) {
        float acc = hb2[tid];
        #pragma unroll
        for (int k = 0; k < LIN_; ++k) acc = fmaf(hw2[tid * LIN_ + k], st1[k], acc);
        st2[tid] = fmaxf(acc, 0.f);
    }
    __syncthreads();
    if (tid == 0) {
        float acc = hb3[0];
        #pragma unroll
        for (int k = 0; k < OUT_; ++k) acc = fmaf(hw3[k], st2[k], acc);
        out[g] = 1.f / (1.f + expf(-acc));
    }
}

// ===========================================================================
extern "C" void kernel_launch(void* const* d_in, const int* in_sizes, int n_in,
                              void* d_out, int out_size, void* d_ws, size_t ws_size,
                              hipStream_t stream)
{
    const float* x     = (const float*)d_in[0];
    const int*   ei    = (const int*)d_in[1];
    const int*   batch = (const int*)d_in[2];
    const float* wA[3] = {(const float*)d_in[3], (const float*)d_in[7], (const float*)d_in[11]};
    const float* bA[3] = {(const float*)d_in[4], (const float*)d_in[8], (const float*)d_in[12]};
    const float* wB[3] = {(const float*)d_in[5], (const float*)d_in[9], (const float*)d_in[13]};
    const float* bB[3] = {(const float*)d_in[6], (const float*)d_in[10], (const float*)d_in[14]};
    const float* bng = (const float*)d_in[15];
    const float* bnb = (const float*)d_in[16];
    const float* hw1 = (const float*)d_in[17];
    const float* hb1 = (const float*)d_in[18];
    const float* hw2 = (const float*)d_in[19];
    const float* hb2 = (const float*)d_in[20];
    const float* hw3 = (const float*)d_in[21];
    const float* hb3 = (const float*)d_in[22];

    const int N = in_sizes[2] / T_;
    const int E = in_sizes[1] / (2 * T_);
    const int G = out_size;
    const int NB = (N + WMSK_) / 128;
    const int gnq = (N + 63) / 64;            // node_q blocks / stat rows
    const float inv_n = 1.0f / (float)N;
    const int gbin = (E + TILE_ - 1) / TILE_;

    const size_t bufN = (size_t)N * DIM_;
    auto need = [&](int tc) -> size_t {
        size_t f = (size_t)tc * bufN                           // agg fp32
                 + (size_t)tc * gnq * 2 * DIM_                 // bstats
                 + (size_t)tc * 2 * DIM_                       // coef
                 + (size_t)G * T_ * DIM_;                      // emb
        size_t hs = 2 * (size_t)tc * bufN;                     // zhA + zhB
        size_t ii = (size_t)tc * NB + 2 * (size_t)tc * N + (size_t)tc * NB * CAP_;
        return f * sizeof(float) + hs * sizeof(unsigned short) + ii * sizeof(int);
    };
    const int tcnt = (need(2) <= ws_size) ? 2 : 1;

    char* ws = (char*)d_ws;
    float* agg    = (float*)ws;                               // tc*N*36 fp32
    float* bstats = agg + (size_t)tcnt * bufN;                // tc*gnq*72
    float* coef   = bstats + (size_t)tcnt * gnq * 2 * DIM_;   // tc*72
    float* emb    = coef + (size_t)tcnt * 2 * DIM_;           // G*72
    unsigned short* zhA = (unsigned short*)(emb + (size_t)G * T_ * DIM_);
    unsigned short* zhB = zhA + (size_t)tcnt * bufN;
    int*   bcnt   = (int*)(zhB + (size_t)tcnt * bufN);        // tc*NB
    int*   rp     = bcnt + (size_t)tcnt * NB;                 // tc*N
    int*   deg    = rp + (size_t)tcnt * N;                    // tc*N
    int*   bbuf   = deg + (size_t)tcnt * N;                   // tc*NB*CAP_

    float* outp = (float*)d_out;

    for (int t0 = 0; t0 < T_; t0 += tcnt) {
        const int tc = tcnt;

        hipMemsetAsync(bcnt, 0, (size_t)tc * NB * sizeof(int), stream);
        binsort_k<<<tc * gbin, 256, 0, stream>>>(ei, t0, gbin, bcnt, bbuf, E, NB);
        csrify_k<<<tc * NB, 256, 0, stream>>>(bcnt, bbuf, rp, deg, N, NB);

        // conv1: fp32 gather of x (self folded), MLP -> bf16 zhA
        gather_k<IN_><<<dim3((N + 95) / 96, tc), 576, 0, stream>>>(
                x + (size_t)t0 * N * IN_, (size_t)N * IN_,
                rp, deg, bbuf, agg, (size_t)N * IN_, N);
        node_q<IN_, false><<<dim3(gnq, tc), 256, 0, stream>>>(
                agg, (size_t)N * IN_, deg, nullptr,
                wA[0], bA[0], wB[0], bB[0], t0,
                zhA, bufN, bstats, gnq, N);
        bnfin_k<<<tc, 288, 0, stream>>>(bstats, gnq, gnq, bng, bnb, t0, 0, coef, inv_n);

        // conv2: bf16 gather zhA -> fp32 agg; MLP -> bf16 zhB
        gather36h_k<<<dim3((N + 63) / 64, tc), 576, 0, stream>>>(
                zhA, bufN, rp, deg, bbuf, agg, bufN, N);
        node_q<DIM_, true><<<dim3(gnq, tc), 256, 0, stream>>>(
                agg, bufN, deg, coef,
                wA[1], bA[1], wB[1], bB[1], t0,
                zhB, bufN, bstats, gnq, N);
        bnfin_k<<<tc, 288, 0, stream>>>(bstats, gnq, gnq, bng, bnb, t0, 1, coef, inv_n);

        // conv3: bf16 gather zhB -> fp32 agg; MLP -> bf16 zhA
        gather36h_k<<<dim3((N + 63) / 64, tc), 576, 0, stream>>>(
                zhB, bufN, rp, deg, bbuf, agg, bufN, N);
        node_q<DIM_, true><<<dim3(gnq, tc), 256, 0, stream>>>(
                agg, bufN, deg, coef,
                wA[2], bA[2], wB[2], bB[2], t0,
                zhA, bufN, bstats, gnq, N);
        bnfin_k<<<tc, 288, 0, stream>>>(bstats, gnq, gnq, bng, bnb, t0, 2, coef, inv_n);

        pool_k<<<dim3(G, tc), 288, 0, stream>>>(zhA, bufN, coef, batch, t0, emb, N);
    }
    head_k<<<G, 64, 0, stream>>>(emb, hw1, hb1, hw2, hb2, hw3, hb3, outp, G);
}

// Round 14
// 651.633 us; speedup vs baseline: 1.3262x; 1.3262x over previous
//
#include <hip/hip_runtime.h>

#define T_   2
#define IN_  6
#define DIM_ 36
#define LIN_ 54
#define OUT_ 18
#define BN_EPS 1e-5f

#define WSH_   7        // bucket width = 128 dst nodes
#define WMSK_  127
#define CAP_   2560     // per-bucket capacity (mean 2046, 11 sigma headroom)
#define TILE_  12288    // edges per binsort block
#define NBMAX_ 1024     // max buckets supported by in-LDS scan

__device__ __forceinline__ unsigned short f2bf(float f) {
    unsigned u = __float_as_uint(f);
    unsigned r = (u + 0x7FFFu + ((u >> 16) & 1u)) >> 16;    // RNE
    return (unsigned short)r;
}
__device__ __forceinline__ float bf2f(unsigned short h) {
    return __uint_as_float(((unsigned)h) << 16);
}
__device__ __forceinline__ unsigned packbf(float a, float b) {
    return (unsigned)f2bf(a) | ((unsigned)f2bf(b) << 16);
}

// ===========================================================================
// binsort_k: bin edges by dst bucket with LDS staging; coalesced packed
// writes (src 17b | dstoff 7b). 16-lane sub-groups in copy-out (R12).
// ===========================================================================
__global__ __launch_bounds__(256) void binsort_k(
    const int* __restrict__ ei, int t0, int gbin,
    int* __restrict__ bcnt, int* __restrict__ bbuf, int ne, int nb)
{
    __shared__ int cntl[NBMAX_], cursl[NBMAX_], gbasel[NBMAX_];
    __shared__ int aux[256];
    __shared__ int sortedl[TILE_];

    const int tid  = threadIdx.x;
    const int lt   = blockIdx.x / gbin;
    const int tile = blockIdx.x % gbin;
    const int base = tile * TILE_;
    const int cnt_e = min(TILE_, ne - base);
    const int* srcp = ei + (size_t)(t0 + lt) * 2 * ne;
    const int* dstp = srcp + ne;
    int* bcnt_t = bcnt + (size_t)lt * nb;

    for (int i = tid; i < NBMAX_; i += 256) cntl[i] = 0;
    __syncthreads();

    for (int i = tid; i < cnt_e; i += 256)
        atomicAdd(&cntl[dstp[base + i] >> WSH_], 1);
    __syncthreads();

    int t4 = tid * 4;
    int c0 = cntl[t4+0], c1 = cntl[t4+1], c2 = cntl[t4+2], c3 = cntl[t4+3];
    int lsum = c0 + c1 + c2 + c3;
    aux[tid] = lsum;
    __syncthreads();
    for (int off = 1; off < 256; off <<= 1) {
        int v = (tid >= off) ? aux[tid - off] : 0;
        __syncthreads();
        aux[tid] += v;
        __syncthreads();
    }
    int eb = aux[tid] - lsum;
    cursl[t4+0] = eb;
    cursl[t4+1] = eb + c0;
    cursl[t4+2] = eb + c0 + c1;
    cursl[t4+3] = eb + c0 + c1 + c2;
    __syncthreads();

    for (int b = tid; b < nb; b += 256) {
        int c = cntl[b];
        gbasel[b] = c ? atomicAdd(&bcnt_t[b], c) : 0;
    }
    __syncthreads();

    for (int i = tid; i < cnt_e; i += 256) {
        int s = srcp[base + i], d = dstp[base + i];
        int p = atomicAdd(&cursl[d >> WSH_], 1);
        sortedl[p] = s | ((d & WMSK_) << 17);
    }
    __syncthreads();

    int grp16 = tid >> 4, ln16 = tid & 15;
    for (int b = grp16; b < nb; b += 16) {
        int c = cntl[b];
        if (!c) continue;
        int lb = cursl[b] - c;
        int gb = gbasel[b];
        size_t ga = ((size_t)lt * nb + b) * CAP_ + gb;
        for (int i = ln16; i < c; i += 16)
            if (gb + i < CAP_) bbuf[ga + i] = sortedl[lb + i];
    }
}

// ===========================================================================
// csrify_k: one block per (t,bucket): sort bucket by dst node in LDS, write
// back coalesced (unpacked src), emit rp (global into bbuf) and deg.
// ===========================================================================
__global__ __launch_bounds__(256) void csrify_k(
    const int* __restrict__ bcnt, int* __restrict__ bbuf,
    int* __restrict__ rp, int* __restrict__ deg, int n, int nb)
{
    __shared__ int ent[CAP_], srt[CAP_];
    __shared__ int cnt[128], cur[128], sc[128];
    const int b = blockIdx.x, tid = threadIdx.x;
    const int blocal = b % nb, lt = b / nb;
    int c = min(bcnt[b], CAP_);
    int* seg = bbuf + (size_t)b * CAP_;

    for (int i = tid; i < c; i += 256) ent[i] = seg[i];
    if (tid < 128) cnt[tid] = 0;
    __syncthreads();
    for (int i = tid; i < c; i += 256)
        atomicAdd(&cnt[(ent[i] >> 17) & WMSK_], 1);
    __syncthreads();
    if (tid < 128) sc[tid] = cnt[tid];
    __syncthreads();
    for (int off = 1; off < 128; off <<= 1) {
        int v = (tid >= off && tid < 128) ? sc[tid - off] : 0;
        __syncthreads();
        if (tid < 128) sc[tid] += v;
        __syncthreads();
    }
    int node0 = blocal << WSH_;
    if (tid < 128) {
        int excl = sc[tid] - cnt[tid];
        cur[tid] = excl;
        if (node0 + tid < n) {
            rp[(size_t)lt * n + node0 + tid]  = b * CAP_ + excl;
            deg[(size_t)lt * n + node0 + tid] = cnt[tid];
        }
    }
    __syncthreads();
    for (int i = tid; i < c; i += 256) {
        int v = ent[i];
        int p = atomicAdd(&cur[(v >> 17) & WMSK_], 1);
        srt[p] = v & 0x1FFFF;
    }
    __syncthreads();
    for (int i = tid; i < c; i += 256) seg[i] = srt[i];
}

// ===========================================================================
// gather_k (conv1, D=6, fp32): agg[i] = x[i] + sum_{nbr} x[nbr].
// ===========================================================================
template<int D>
__global__ __launch_bounds__(576) void gather_k(
        const float* __restrict__ hbase, size_t hstride,
        const int* __restrict__ rp, const int* __restrict__ deg,
        const int* __restrict__ csr, float* __restrict__ agg,
        size_t astride, int n)
{
    const int NPB = 576 / D;
    const int slot = blockIdx.y;
    const float* h = hbase + (size_t)slot * hstride;
    int g = blockIdx.x * NPB + threadIdx.x / D;
    int lane = threadIdx.x % D;
    if (g >= n) return;
    int lo = rp[(size_t)slot * n + g], hi = lo + deg[(size_t)slot * n + g];
    float a0 = h[(size_t)g * D + lane], a1 = 0.f, a2 = 0.f, a3 = 0.f;
    int e = lo;
    for (; e + 3 < hi; e += 4) {
        int s0 = csr[e], s1 = csr[e + 1], s2 = csr[e + 2], s3 = csr[e + 3];
        a0 += h[(size_t)s0 * D + lane];
        a1 += h[(size_t)s1 * D + lane];
        a2 += h[(size_t)s2 * D + lane];
        a3 += h[(size_t)s3 * D + lane];
    }
    for (; e < hi; ++e) a0 += h[(size_t)csr[e] * D + lane];
    agg[(size_t)slot * astride + (size_t)g * D + lane] = (a0 + a1) + (a2 + a3);
}

// ===========================================================================
// gather36h_k: bf16 rows, 9 lanes/node (4 features/lane via uint2 = 8B/lane).
// agg[i] = self + sum_nbr, fp32 out. Barrier-free, register accumulation.
// (Triple-confirmed R5/R9/R11: must NOT be fused with the MLP.)
// ===========================================================================
__global__ __launch_bounds__(576) void gather36h_k(
        const unsigned short* __restrict__ zh, size_t zhstride,
        const int* __restrict__ rp, const int* __restrict__ deg,
        const int* __restrict__ csr, float* __restrict__ agg,
        size_t astride, int n)
{
    const int slot = blockIdx.y;
    const unsigned short* zhs = zh + (size_t)slot * zhstride;
    int g = blockIdx.x * 64 + threadIdx.x / 9;
    int lane = threadIdx.x % 9;
    if (g >= n) return;
    size_t off = (size_t)slot * n + g;
    int lo = rp[off], hi = lo + deg[off];

    uint2 v = *reinterpret_cast<const uint2*>(zhs + (size_t)g * DIM_ + 4 * lane);
    float a0 = bf2f((unsigned short)(v.x & 0xffff));
    float a1 = bf2f((unsigned short)(v.x >> 16));
    float a2 = bf2f((unsigned short)(v.y & 0xffff));
    float a3 = bf2f((unsigned short)(v.y >> 16));
    float b0 = 0.f, b1 = 0.f, b2 = 0.f, b3 = 0.f;

    int e = lo;
    for (; e + 1 < hi; e += 2) {
        int s0 = csr[e], s1 = csr[e + 1];
        uint2 u0 = *reinterpret_cast<const uint2*>(zhs + (size_t)s0 * DIM_ + 4 * lane);
        uint2 u1 = *reinterpret_cast<const uint2*>(zhs + (size_t)s1 * DIM_ + 4 * lane);
        a0 += bf2f((unsigned short)(u0.x & 0xffff));
        a1 += bf2f((unsigned short)(u0.x >> 16));
        a2 += bf2f((unsigned short)(u0.y & 0xffff));
        a3 += bf2f((unsigned short)(u0.y >> 16));
        b0 += bf2f((unsigned short)(u1.x & 0xffff));
        b1 += bf2f((unsigned short)(u1.x >> 16));
        b2 += bf2f((unsigned short)(u1.y & 0xffff));
        b3 += bf2f((unsigned short)(u1.y >> 16));
    }
    if (e < hi) {
        uint2 u0 = *reinterpret_cast<const uint2*>(zhs + (size_t)csr[e] * DIM_ + 4 * lane);
        a0 += bf2f((unsigned short)(u0.x & 0xffff));
        a1 += bf2f((unsigned short)(u0.x >> 16));
        a2 += bf2f((unsigned short)(u0.y & 0xffff));
        a3 += bf2f((unsigned short)(u0.y >> 16));
    }
    float4 r; r.x = a0 + b0; r.y = a1 + b1; r.z = a2 + b2; r.w = a3 + b3;
    *reinterpret_cast<float4*>(agg + (size_t)slot * astride + (size_t)g * DIM_ + 4 * lane) = r;
}

// ===========================================================================
// node_s: node MLP parallelized across WAVES (not lanes — R13's lane split
// broke weight wave-uniformity -> per-lane VMEM weight loads, 137us).
// 256 thr = 4 waves x 64 nodes. Wave w computes output rows 9w..9w+8 for
// all 64 nodes; w = readfirstlane(tid>>6) keeps weight indices provably
// wave-uniform -> s_load/SGPR path. hin & y staged in LDS [64][37]
// (stride-37 = conflict-free per-lane rows; sca[k] same-addr broadcast).
// Barriers carry UNIFORM work only (no degree-variant phase).
// ===========================================================================
template<int DIN, bool AFF>
__global__ __launch_bounds__(256) void node_s(
    const float* __restrict__ agg, size_t astride,
    const int* __restrict__ deg,
    const float* __restrict__ coef,
    const float* __restrict__ wAb, const float* __restrict__ bAb,
    const float* __restrict__ wBb, const float* __restrict__ bBb,
    int t0,
    unsigned short* __restrict__ zho, size_t zstride,
    float* __restrict__ bstats, int gn, int n)
{
    __shared__ float hl[64][DIN + 1];
    __shared__ float yl[64][DIM_ + 1];
    __shared__ float sca[DIM_], scb2[DIM_];
    __shared__ float sst[4][18];

    const int tid = threadIdx.x;
    const int w = __builtin_amdgcn_readfirstlane(tid >> 6);   // wave id (SGPR)
    const int lane = tid & 63;
    const int slot = blockIdx.y;
    const int t = t0 + slot;
    const float* wa = wAb + (size_t)t * DIM_ * DIN;
    const float* ba = bAb + (size_t)t * DIM_;
    const float* wb = wBb + (size_t)t * DIM_ * DIM_;
    const float* bb = bBb + (size_t)t * DIM_;

    const int node0 = blockIdx.x * 64;
    const int node = node0 + lane;
    const bool act = node < n;

    if constexpr (AFF) {
        if (tid < 2 * DIM_) {
            float v = coef[(size_t)slot * 2 * DIM_ + tid];
            if (tid < DIM_) sca[tid] = v; else scb2[tid - DIM_] = v;
        }
    }

    // cooperative coalesced load of the 64 hin rows
    {
        const float* ag = agg + (size_t)slot * astride + (size_t)node0 * DIN;
        int lim = (n - node0) * DIN;          // valid elements in this block
        for (int i = tid; i < 64 * DIN; i += 256) {
            float v = (i < lim) ? ag[i] : 0.f;
            hl[i / DIN][i % DIN] = v;
        }
    }
    float ds = 0.f;
    if (AFF && act) ds = 1.0f + (float)deg[(size_t)slot * n + node];
    __syncthreads();

    // layer A: wave w -> rows 9w..9w+8, node = lane
    float ya[9];
    #pragma unroll
    for (int r = 0; r < 9; ++r) ya[r] = ba[9 * w + r];
    for (int k = 0; k < DIN; ++k) {
        float hv = hl[lane][k];
        if constexpr (AFF) hv = sca[k] * hv + ds * scb2[k];
        #pragma unroll
        for (int r = 0; r < 9; ++r)
            ya[r] = fmaf(wa[(9 * w + r) * DIN + k], hv, ya[r]);
    }
    #pragma unroll
    for (int r = 0; r < 9; ++r) yl[lane][9 * w + r] = fmaxf(ya[r], 0.f);
    __syncthreads();

    // layer B
    float ob[9];
    #pragma unroll
    for (int r = 0; r < 9; ++r) ob[r] = bb[9 * w + r];
    for (int k = 0; k < DIM_; ++k) {
        float yv = yl[lane][k];
        #pragma unroll
        for (int r = 0; r < 9; ++r)
            ob[r] = fmaf(wb[(9 * w + r) * DIM_ + k], yv, ob[r]);
    }
    #pragma unroll
    for (int r = 0; r < 9; ++r) ob[r] = act ? fmaxf(ob[r], 0.f) : 0.f;

    // BN stats: reduce over 64 nodes within the wave; lane0 owns 9 feats
    {
        float ss[9], sq[9];
        #pragma unroll
        for (int r = 0; r < 9; ++r) { ss[r] = ob[r]; sq[r] = ob[r] * ob[r]; }
        #pragma unroll
        for (int r = 0; r < 9; ++r) {
            for (int off = 32; off; off >>= 1) {
                ss[r] += __shfl_down(ss[r], off);
                sq[r] += __shfl_down(sq[r], off);
            }
        }
        if (lane == 0) {
            #pragma unroll
            for (int r = 0; r < 9; ++r) { sst[w][r] = ss[r]; sst[w][9 + r] = sq[r]; }
        }
    }

    __syncthreads();                 // all yl reads done -> safe to overwrite
    #pragma unroll
    for (int r = 0; r < 9; ++r) yl[lane][9 * w + r] = ob[r];
    __syncthreads();

    // coalesced bf16 z write from staging
    {
        unsigned short* zb = zho + (size_t)slot * zstride + (size_t)node0 * DIM_;
        for (int i = tid; i < 64 * 18; i += 256) {
            int nd = i / 18, up = i % 18;
            if (node0 + nd < n)
                reinterpret_cast<unsigned*>(zb)[i] =
                    packbf(yl[nd][2 * up], yl[nd][2 * up + 1]);
        }
    }

    if (tid < 2 * DIM_) {
        int f = (tid < DIM_) ? tid : tid - DIM_;
        float v = (tid < DIM_) ? sst[f / 9][f % 9] : sst[f / 9][9 + f % 9];
        bstats[((size_t)slot * gn + blockIdx.x) * (2 * DIM_) + tid] = v;
    }
}

// ===========================================================================
// bnfin_k: reduce nrows stat rows -> fused affine coef {a, b2}. Grid (tc).
// ===========================================================================
__global__ __launch_bounds__(288) void bnfin_k(
    const float* __restrict__ bstats, int nrows, int rstride,
    const float* __restrict__ bng, const float* __restrict__ bnb,
    int t0, int c, float* __restrict__ coef, float inv_n)
{
    __shared__ float part[4][2 * DIM_];
    const int slot = blockIdx.x;
    const int t = t0 + slot;
    int tid = threadIdx.x;
    int col = tid % (2 * DIM_), quarter = tid / (2 * DIM_);
    const float* bs = bstats + (size_t)slot * rstride * (2 * DIM_);
    float s = 0.f;
    for (int i = quarter; i < nrows; i += 4) s += bs[(size_t)i * (2 * DIM_) + col];
    part[quarter][col] = s;
    __syncthreads();
    if (tid < 2 * DIM_)
        part[0][tid] = part[0][tid] + part[1][tid] + part[2][tid] + part[3][tid];
    __syncthreads();
    if (tid < DIM_) {
        float mean = part[0][tid] * inv_n;
        float var  = part[0][DIM_ + tid] * inv_n - mean * mean;
        float aa   = bng[((size_t)t * 3 + c) * DIM_ + tid] / sqrtf(var + BN_EPS);
        coef[(size_t)slot * 2 * DIM_ + tid]        = aa;
        coef[(size_t)slot * 2 * DIM_ + DIM_ + tid] = bnb[((size_t)t * 3 + c) * DIM_ + tid] - aa * mean;
    }
}

// ===========================================================================
// pool_k: per-graph mean pool over bf16 z (batch sorted), conv-3 coef.
// ===========================================================================
__global__ __launch_bounds__(288) void pool_k(
    const unsigned short* __restrict__ zh, size_t zstride,
    const float* __restrict__ coef,
    const int* __restrict__ batch, int t0,
    float* __restrict__ emb, int n)
{
    __shared__ int slo, shi;
    __shared__ float sp0[16][19], sp1[16][19];
    const int slot = blockIdx.y;
    const int t = t0 + slot;
    const int* bt = batch + (size_t)t * n;
    const unsigned short* zt = zh + (size_t)slot * zstride;
    const float* ca  = coef + (size_t)slot * 2 * DIM_;
    const float* cb2 = ca + DIM_;

    int g = blockIdx.x;
    int tid = threadIdx.x;
    if (tid == 0) {
        int lo = 0, hi = n;
        while (lo < hi) { int m = (lo + hi) >> 1; if (bt[m] < g) lo = m + 1; else hi = m; }
        slo = lo;
        int lo2 = lo, hi2 = n;
        while (lo2 < hi2) { int m = (lo2 + hi2) >> 1; if (bt[m] < g + 1) lo2 = m + 1; else hi2 = m; }
        shi = lo2;
    }
    __syncthreads();
    int lo = slo, hi = shi;
    int fp = tid % 18, j = tid / 18;
    float acc0 = 0.f, acc1 = 0.f;
    for (int i = lo + j; i < hi; i += 16) {
        unsigned v = *reinterpret_cast<const unsigned*>(zt + (size_t)i * DIM_ + 2 * fp);
        acc0 += bf2f((unsigned short)(v & 0xffff));
        acc1 += bf2f((unsigned short)(v >> 16));
    }
    sp0[j][fp] = acc0;
    sp1[j][fp] = acc1;
    __syncthreads();
    if (tid < DIM_) {
        int f = tid, fpair = f >> 1, hi_ = f & 1;
        float s = 0.f;
        #pragma unroll
        for (int jj = 0; jj < 16; ++jj)
            s += hi_ ? sp1[jj][fpair] : sp0[jj][fpair];
        int cnt = hi - lo;
        float val = 0.f;
        if (cnt > 0) val = ca[f] * (s / (float)cnt) + cb2[f];
        emb[(size_t)g * (T_ * DIM_) + t * DIM_ + f] = val;
    }
}

// ===========================================================================
// head_k: one 64-thread block per graph, layers staged through LDS.
// ===========================================================================
__global__ __launch_bounds__(64) void head_k(
    const float* __restrict__ emb,
    const float* __restrict__ hw1, const float* __restrict__ hb1,
    const float* __restrict__ hw2, const float* __restrict__ hb2,
    const float* __restrict__ hw3, const float* __restrict__ hb3,
    float* __restrict__ out, int ng)
{
    const int EMB = T_ * DIM_;
    int g = blockIdx.x;
    if (g >= ng) return;
    __shared__ float se[EMB], st1[LIN_], st2[OUT_];
    int tid = threadIdx.x;
    for (int i = tid; i < EMB; i += 64) se[i] = emb[(size_t)g * EMB + i];
    __syncthreads();
    if (tid < LIN_) {
        float acc = hb1[tid];
        #pragma unroll
        for (int k = 0; k < EMB; ++k) acc = fmaf(hw1[tid * EMB + k], se[k], acc);
        st1[tid] = fmaxf(acc, 0.f);
    }
    __syncthreads();
    if (tid < OUT_) {
        float acc = hb2[tid];
        #pragma unroll
        for (int k = 0; k < LIN_; ++k) acc = fmaf(hw2[tid * LIN_ + k], st1[k], acc);
        st2[tid] = fmaxf(acc, 0.f);
    }
    __syncthreads();
    if (tid == 0) {
        float acc = hb3[0];
        #pragma unroll
        for (int k = 0; k < OUT_; ++k) acc = fmaf(hw3[k], st2[k], acc);
        out[g] = 1.f / (1.f + expf(-acc));
    }
}

// ===========================================================================
extern "C" void kernel_launch(void* const* d_in, const int* in_sizes, int n_in,
                              void* d_out, int out_size, void* d_ws, size_t ws_size,
                              hipStream_t stream)
{
    const float* x     = (const float*)d_in[0];
    const int*   ei    = (const int*)d_in[1];
    const int*   batch = (const int*)d_in[2];
    const float* wA[3] = {(const float*)d_in[3], (const float*)d_in[7], (const float*)d_in[11]};
    const float* bA[3] = {(const float*)d_in[4], (const float*)d_in[8], (const float*)d_in[12]};
    const float* wB[3] = {(const float*)d_in[5], (const float*)d_in[9], (const float*)d_in[13]};
    const float* bB[3] = {(const float*)d_in[6], (const float*)d_in[10], (const float*)d_in[14]};
    const float* bng = (const float*)d_in[15];
    const float* bnb = (const float*)d_in[16];
    const float* hw1 = (const float*)d_in[17];
    const float* hb1 = (const float*)d_in[18];
    const float* hw2 = (const float*)d_in[19];
    const float* hb2 = (const float*)d_in[20];
    const float* hw3 = (const float*)d_in[21];
    const float* hb3 = (const float*)d_in[22];

    const int N = in_sizes[2] / T_;
    const int E = in_sizes[1] / (2 * T_);
    const int G = out_size;
    const int NB = (N + WMSK_) / 128;
    const int gnq = (N + 63) / 64;            // node_s blocks / stat rows
    const float inv_n = 1.0f / (float)N;
    const int gbin = (E + TILE_ - 1) / TILE_;

    const size_t bufN = (size_t)N * DIM_;
    auto need = [&](int tc) -> size_t {
        size_t f = (size_t)tc * bufN                           // agg fp32
                 + (size_t)tc * gnq * 2 * DIM_                 // bstats
                 + (size_t)tc * 2 * DIM_                       // coef
                 + (size_t)G * T_ * DIM_;                      // emb
        size_t hs = 2 * (size_t)tc * bufN;                     // zhA + zhB
        size_t ii = (size_t)tc * NB + 2 * (size_t)tc * N + (size_t)tc * NB * CAP_;
        return f * sizeof(float) + hs * sizeof(unsigned short) + ii * sizeof(int);
    };
    const int tcnt = (need(2) <= ws_size) ? 2 : 1;

    char* ws = (char*)d_ws;
    float* agg    = (float*)ws;                               // tc*N*36 fp32
    float* bstats = agg + (size_t)tcnt * bufN;                // tc*gnq*72
    float* coef   = bstats + (size_t)tcnt * gnq * 2 * DIM_;   // tc*72
    float* emb    = coef + (size_t)tcnt * 2 * DIM_;           // G*72
    unsigned short* zhA = (unsigned short*)(emb + (size_t)G * T_ * DIM_);
    unsigned short* zhB = zhA + (size_t)tcnt * bufN;
    int*   bcnt   = (int*)(zhB + (size_t)tcnt * bufN);        // tc*NB
    int*   rp     = bcnt + (size_t)tcnt * NB;                 // tc*N
    int*   deg    = rp + (size_t)tcnt * N;                    // tc*N
    int*   bbuf   = deg + (size_t)tcnt * N;                   // tc*NB*CAP_

    float* outp = (float*)d_out;

    for (int t0 = 0; t0 < T_; t0 += tcnt) {
        const int tc = tcnt;

        hipMemsetAsync(bcnt, 0, (size_t)tc * NB * sizeof(int), stream);
        binsort_k<<<tc * gbin, 256, 0, stream>>>(ei, t0, gbin, bcnt, bbuf, E, NB);
        csrify_k<<<tc * NB, 256, 0, stream>>>(bcnt, bbuf, rp, deg, N, NB);

        // conv1: fp32 gather of x (self folded), MLP -> bf16 zhA
        gather_k<IN_><<<dim3((N + 95) / 96, tc), 576, 0, stream>>>(
                x + (size_t)t0 * N * IN_, (size_t)N * IN_,
                rp, deg, bbuf, agg, (size_t)N * IN_, N);
        node_s<IN_, false><<<dim3(gnq, tc), 256, 0, stream>>>(
                agg, (size_t)N * IN_, deg, nullptr,
                wA[0], bA[0], wB[0], bB[0], t0,
                zhA, bufN, bstats, gnq, N);
        bnfin_k<<<tc, 288, 0, stream>>>(bstats, gnq, gnq, bng, bnb, t0, 0, coef, inv_n);

        // conv2: bf16 gather zhA -> fp32 agg; MLP -> bf16 zhB
        gather36h_k<<<dim3((N + 63) / 64, tc), 576, 0, stream>>>(
                zhA, bufN, rp, deg, bbuf, agg, bufN, N);
        node_s<DIM_, true><<<dim3(gnq, tc), 256, 0, stream>>>(
                agg, bufN, deg, coef,
                wA[1], bA[1], wB[1], bB[1], t0,
                zhB, bufN, bstats, gnq, N);
        bnfin_k<<<tc, 288, 0, stream>>>(bstats, gnq, gnq, bng, bnb, t0, 1, coef, inv_n);

        // conv3: bf16 gather zhB -> fp32 agg; MLP -> bf16 zhA
        gather36h_k<<<dim3((N + 63) / 64, tc), 576, 0, stream>>>(
                zhB, bufN, rp, deg, bbuf, agg, bufN, N);
        node_s<DIM_, true><<<dim3(gnq, tc), 256, 0, stream>>>(
                agg, bufN, deg, coef,
                wA[2], bA[2], wB[2], bB[2], t0,
                zhA, bufN, bstats, gnq, N);
        bnfin_k<<<tc, 288, 0, stream>>>(bstats, gnq, gnq, bng, bnb, t0, 2, coef, inv_n);

        pool_k<<<dim3(G, tc), 288, 0, stream>>>(zhA, bufN, coef, batch, t0, emb, N);
    }
    head_k<<<G, 64, 0, stream>>>(emb, hw1, hb1, hw2, hb2, hw3, hb3, outp, G);
}

// Round 15
// 399.910 us; speedup vs baseline: 2.1610x; 1.6295x over previous
//
#include <hip/hip_runtime.h>

#define T_   2
#define IN_  6
#define DIM_ 36
#define LIN_ 54
#define OUT_ 18
#define BN_EPS 1e-5f

#define WSH_   7        // bucket width = 128 dst nodes
#define WMSK_  127
#define CAP_   2560     // per-bucket capacity (mean 2046, 11 sigma headroom)
#define TILE_  12288    // edges per binsort block
#define NBMAX_ 1024     // max buckets supported by in-LDS scan

__device__ __forceinline__ unsigned short f2bf(float f) {
    unsigned u = __float_as_uint(f);
    unsigned r = (u + 0x7FFFu + ((u >> 16) & 1u)) >> 16;    // RNE
    return (unsigned short)r;
}
__device__ __forceinline__ float bf2f(unsigned short h) {
    return __uint_as_float(((unsigned)h) << 16);
}
__device__ __forceinline__ unsigned packbf(float a, float b) {
    return (unsigned)f2bf(a) | ((unsigned)f2bf(b) << 16);
}

// ===========================================================================
// binsort_k: bin edges by dst bucket with LDS staging; coalesced packed
// writes (src 17b | dstoff 7b). 16-lane sub-groups in copy-out (R12).
// ===========================================================================
__global__ __launch_bounds__(256) void binsort_k(
    const int* __restrict__ ei, int t0, int gbin,
    int* __restrict__ bcnt, int* __restrict__ bbuf, int ne, int nb)
{
    __shared__ int cntl[NBMAX_], cursl[NBMAX_], gbasel[NBMAX_];
    __shared__ int aux[256];
    __shared__ int sortedl[TILE_];

    const int tid  = threadIdx.x;
    const int lt   = blockIdx.x / gbin;
    const int tile = blockIdx.x % gbin;
    const int base = tile * TILE_;
    const int cnt_e = min(TILE_, ne - base);
    const int* srcp = ei + (size_t)(t0 + lt) * 2 * ne;
    const int* dstp = srcp + ne;
    int* bcnt_t = bcnt + (size_t)lt * nb;

    for (int i = tid; i < NBMAX_; i += 256) cntl[i] = 0;
    __syncthreads();

    for (int i = tid; i < cnt_e; i += 256)
        atomicAdd(&cntl[dstp[base + i] >> WSH_], 1);
    __syncthreads();

    int t4 = tid * 4;
    int c0 = cntl[t4+0], c1 = cntl[t4+1], c2 = cntl[t4+2], c3 = cntl[t4+3];
    int lsum = c0 + c1 + c2 + c3;
    aux[tid] = lsum;
    __syncthreads();
    for (int off = 1; off < 256; off <<= 1) {
        int v = (tid >= off) ? aux[tid - off] : 0;
        __syncthreads();
        aux[tid] += v;
        __syncthreads();
    }
    int eb = aux[tid] - lsum;
    cursl[t4+0] = eb;
    cursl[t4+1] = eb + c0;
    cursl[t4+2] = eb + c0 + c1;
    cursl[t4+3] = eb + c0 + c1 + c2;
    __syncthreads();

    for (int b = tid; b < nb; b += 256) {
        int c = cntl[b];
        gbasel[b] = c ? atomicAdd(&bcnt_t[b], c) : 0;
    }
    __syncthreads();

    for (int i = tid; i < cnt_e; i += 256) {
        int s = srcp[base + i], d = dstp[base + i];
        int p = atomicAdd(&cursl[d >> WSH_], 1);
        sortedl[p] = s | ((d & WMSK_) << 17);
    }
    __syncthreads();

    int grp16 = tid >> 4, ln16 = tid & 15;
    for (int b = grp16; b < nb; b += 16) {
        int c = cntl[b];
        if (!c) continue;
        int lb = cursl[b] - c;
        int gb = gbasel[b];
        size_t ga = ((size_t)lt * nb + b) * CAP_ + gb;
        for (int i = ln16; i < c; i += 16)
            if (gb + i < CAP_) bbuf[ga + i] = sortedl[lb + i];
    }
}

// ===========================================================================
// csrify_k: one block per (t,bucket): sort bucket by dst node in LDS, write
// back coalesced (unpacked src), emit rp (global into bbuf) and deg.
// ===========================================================================
__global__ __launch_bounds__(256) void csrify_k(
    const int* __restrict__ bcnt, int* __restrict__ bbuf,
    int* __restrict__ rp, int* __restrict__ deg, int n, int nb)
{
    __shared__ int ent[CAP_], srt[CAP_];
    __shared__ int cnt[128], cur[128], sc[128];
    const int b = blockIdx.x, tid = threadIdx.x;
    const int blocal = b % nb, lt = b / nb;
    int c = min(bcnt[b], CAP_);
    int* seg = bbuf + (size_t)b * CAP_;

    for (int i = tid; i < c; i += 256) ent[i] = seg[i];
    if (tid < 128) cnt[tid] = 0;
    __syncthreads();
    for (int i = tid; i < c; i += 256)
        atomicAdd(&cnt[(ent[i] >> 17) & WMSK_], 1);
    __syncthreads();
    if (tid < 128) sc[tid] = cnt[tid];
    __syncthreads();
    for (int off = 1; off < 128; off <<= 1) {
        int v = (tid >= off && tid < 128) ? sc[tid - off] : 0;
        __syncthreads();
        if (tid < 128) sc[tid] += v;
        __syncthreads();
    }
    int node0 = blocal << WSH_;
    if (tid < 128) {
        int excl = sc[tid] - cnt[tid];
        cur[tid] = excl;
        if (node0 + tid < n) {
            rp[(size_t)lt * n + node0 + tid]  = b * CAP_ + excl;
            deg[(size_t)lt * n + node0 + tid] = cnt[tid];
        }
    }
    __syncthreads();
    for (int i = tid; i < c; i += 256) {
        int v = ent[i];
        int p = atomicAdd(&cur[(v >> 17) & WMSK_], 1);
        srt[p] = v & 0x1FFFF;
    }
    __syncthreads();
    for (int i = tid; i < c; i += 256) seg[i] = srt[i];
}

// ===========================================================================
// gather_k (conv1, D=6, fp32): agg[i] = x[i] + sum_{nbr} x[nbr].
// ===========================================================================
template<int D>
__global__ __launch_bounds__(576) void gather_k(
        const float* __restrict__ hbase, size_t hstride,
        const int* __restrict__ rp, const int* __restrict__ deg,
        const int* __restrict__ csr, float* __restrict__ agg,
        size_t astride, int n)
{
    const int NPB = 576 / D;
    const int slot = blockIdx.y;
    const float* h = hbase + (size_t)slot * hstride;
    int g = blockIdx.x * NPB + threadIdx.x / D;
    int lane = threadIdx.x % D;
    if (g >= n) return;
    int lo = rp[(size_t)slot * n + g], hi = lo + deg[(size_t)slot * n + g];
    float a0 = h[(size_t)g * D + lane], a1 = 0.f, a2 = 0.f, a3 = 0.f;
    int e = lo;
    for (; e + 3 < hi; e += 4) {
        int s0 = csr[e], s1 = csr[e + 1], s2 = csr[e + 2], s3 = csr[e + 3];
        a0 += h[(size_t)s0 * D + lane];
        a1 += h[(size_t)s1 * D + lane];
        a2 += h[(size_t)s2 * D + lane];
        a3 += h[(size_t)s3 * D + lane];
    }
    for (; e < hi; ++e) a0 += h[(size_t)csr[e] * D + lane];
    agg[(size_t)slot * astride + (size_t)g * D + lane] = (a0 + a1) + (a2 + a3);
}

// ===========================================================================
// gather36h_k: bf16 rows, 9 lanes/node (4 features/lane via uint2 = 8B/lane).
// agg[i] = self + sum_nbr, fp32 out. Barrier-free, register accumulation.
// (Triple-confirmed R5/R9/R11: must NOT be fused with the MLP.)
// ===========================================================================
__global__ __launch_bounds__(576) void gather36h_k(
        const unsigned short* __restrict__ zh, size_t zhstride,
        const int* __restrict__ rp, const int* __restrict__ deg,
        const int* __restrict__ csr, float* __restrict__ agg,
        size_t astride, int n)
{
    const int slot = blockIdx.y;
    const unsigned short* zhs = zh + (size_t)slot * zhstride;
    int g = blockIdx.x * 64 + threadIdx.x / 9;
    int lane = threadIdx.x % 9;
    if (g >= n) return;
    size_t off = (size_t)slot * n + g;
    int lo = rp[off], hi = lo + deg[off];

    uint2 v = *reinterpret_cast<const uint2*>(zhs + (size_t)g * DIM_ + 4 * lane);
    float a0 = bf2f((unsigned short)(v.x & 0xffff));
    float a1 = bf2f((unsigned short)(v.x >> 16));
    float a2 = bf2f((unsigned short)(v.y & 0xffff));
    float a3 = bf2f((unsigned short)(v.y >> 16));
    float b0 = 0.f, b1 = 0.f, b2 = 0.f, b3 = 0.f;

    int e = lo;
    for (; e + 1 < hi; e += 2) {
        int s0 = csr[e], s1 = csr[e + 1];
        uint2 u0 = *reinterpret_cast<const uint2*>(zhs + (size_t)s0 * DIM_ + 4 * lane);
        uint2 u1 = *reinterpret_cast<const uint2*>(zhs + (size_t)s1 * DIM_ + 4 * lane);
        a0 += bf2f((unsigned short)(u0.x & 0xffff));
        a1 += bf2f((unsigned short)(u0.x >> 16));
        a2 += bf2f((unsigned short)(u0.y & 0xffff));
        a3 += bf2f((unsigned short)(u0.y >> 16));
        b0 += bf2f((unsigned short)(u1.x & 0xffff));
        b1 += bf2f((unsigned short)(u1.x >> 16));
        b2 += bf2f((unsigned short)(u1.y & 0xffff));
        b3 += bf2f((unsigned short)(u1.y >> 16));
    }
    if (e < hi) {
        uint2 u0 = *reinterpret_cast<const uint2*>(zhs + (size_t)csr[e] * DIM_ + 4 * lane);
        a0 += bf2f((unsigned short)(u0.x & 0xffff));
        a1 += bf2f((unsigned short)(u0.x >> 16));
        a2 += bf2f((unsigned short)(u0.y & 0xffff));
        a3 += bf2f((unsigned short)(u0.y >> 16));
    }
    float4 r; r.x = a0 + b0; r.y = a1 + b1; r.z = a2 + b2; r.w = a3 + b3;
    *reinterpret_cast<float4*>(agg + (size_t)slot * astride + (size_t)g * DIM_ + 4 * lane) = r;
}

// ===========================================================================
// node_s: node MLP parallelized across WAVES (R13's lane split broke weight
// wave-uniformity). 256 thr = 4 waves x 64 nodes; wave w computes rows
// 9w..9w+8 for all 64 nodes; weights stay on the s_load/SGPR path.
// ===========================================================================
template<int DIN, bool AFF>
__global__ __launch_bounds__(256) void node_s(
    const float* __restrict__ agg, size_t astride,
    const int* __restrict__ deg,
    const float* __restrict__ coef,
    const float* __restrict__ wAb, const float* __restrict__ bAb,
    const float* __restrict__ wBb, const float* __restrict__ bBb,
    int t0,
    unsigned short* __restrict__ zho, size_t zstride,
    float* __restrict__ bstats, int gn, int n)
{
    __shared__ float hl[64][DIN + 1];
    __shared__ float yl[64][DIM_ + 1];
    __shared__ float sca[DIM_], scb2[DIM_];
    __shared__ float sst[4][18];

    const int tid = threadIdx.x;
    const int w = __builtin_amdgcn_readfirstlane(tid >> 6);   // wave id (SGPR)
    const int lane = tid & 63;
    const int slot = blockIdx.y;
    const int t = t0 + slot;
    const float* wa = wAb + (size_t)t * DIM_ * DIN;
    const float* ba = bAb + (size_t)t * DIM_;
    const float* wb = wBb + (size_t)t * DIM_ * DIM_;
    const float* bb = bBb + (size_t)t * DIM_;

    const int node0 = blockIdx.x * 64;
    const int node = node0 + lane;
    const bool act = node < n;

    if constexpr (AFF) {
        if (tid < 2 * DIM_) {
            float v = coef[(size_t)slot * 2 * DIM_ + tid];
            if (tid < DIM_) sca[tid] = v; else scb2[tid - DIM_] = v;
        }
    }

    // cooperative coalesced load of the 64 hin rows
    {
        const float* ag = agg + (size_t)slot * astride + (size_t)node0 * DIN;
        int lim = (n - node0) * DIN;
        for (int i = tid; i < 64 * DIN; i += 256) {
            float v = (i < lim) ? ag[i] : 0.f;
            hl[i / DIN][i % DIN] = v;
        }
    }
    float ds = 0.f;
    if (AFF && act) ds = 1.0f + (float)deg[(size_t)slot * n + node];
    __syncthreads();

    // layer A: wave w -> rows 9w..9w+8, node = lane
    float ya[9];
    #pragma unroll
    for (int r = 0; r < 9; ++r) ya[r] = ba[9 * w + r];
    for (int k = 0; k < DIN; ++k) {
        float hv = hl[lane][k];
        if constexpr (AFF) hv = sca[k] * hv + ds * scb2[k];
        #pragma unroll
        for (int r = 0; r < 9; ++r)
            ya[r] = fmaf(wa[(9 * w + r) * DIN + k], hv, ya[r]);
    }
    #pragma unroll
    for (int r = 0; r < 9; ++r) yl[lane][9 * w + r] = fmaxf(ya[r], 0.f);
    __syncthreads();

    // layer B
    float ob[9];
    #pragma unroll
    for (int r = 0; r < 9; ++r) ob[r] = bb[9 * w + r];
    for (int k = 0; k < DIM_; ++k) {
        float yv = yl[lane][k];
        #pragma unroll
        for (int r = 0; r < 9; ++r)
            ob[r] = fmaf(wb[(9 * w + r) * DIM_ + k], yv, ob[r]);
    }
    #pragma unroll
    for (int r = 0; r < 9; ++r) ob[r] = act ? fmaxf(ob[r], 0.f) : 0.f;

    // BN stats: reduce over 64 nodes within the wave; lane0 owns 9 feats
    {
        float ss[9], sq[9];
        #pragma unroll
        for (int r = 0; r < 9; ++r) { ss[r] = ob[r]; sq[r] = ob[r] * ob[r]; }
        #pragma unroll
        for (int r = 0; r < 9; ++r) {
            for (int off = 32; off; off >>= 1) {
                ss[r] += __shfl_down(ss[r], off);
                sq[r] += __shfl_down(sq[r], off);
            }
        }
        if (lane == 0) {
            #pragma unroll
            for (int r = 0; r < 9; ++r) { sst[w][r] = ss[r]; sst[w][9 + r] = sq[r]; }
        }
    }

    __syncthreads();                 // all yl reads done -> safe to overwrite
    #pragma unroll
    for (int r = 0; r < 9; ++r) yl[lane][9 * w + r] = ob[r];
    __syncthreads();

    // coalesced bf16 z write from staging
    {
        unsigned short* zb = zho + (size_t)slot * zstride + (size_t)node0 * DIM_;
        for (int i = tid; i < 64 * 18; i += 256) {
            int nd = i / 18, up = i % 18;
            if (node0 + nd < n)
                reinterpret_cast<unsigned*>(zb)[i] =
                    packbf(yl[nd][2 * up], yl[nd][2 * up + 1]);
        }
    }

    if (tid < 2 * DIM_) {
        int f = (tid < DIM_) ? tid : tid - DIM_;
        float v = (tid < DIM_) ? sst[f / 9][f % 9] : sst[f / 9][9 + f % 9];
        bstats[((size_t)slot * gn + blockIdx.x) * (2 * DIM_) + tid] = v;
    }
}

// ===========================================================================
// bnred_k: stage-1 reduce of bstats[gn rows][72] -> psum[slot][72].
// Grid (9, tc) x 256: block owns 8 columns; 32 lanes/column sum rows
// strided by 32 with 4 independent accumulators (R14's bnfin was a serial
// load+add chain, 100us on a 2-block grid). shfl-tree, direct store.
// ===========================================================================
__global__ __launch_bounds__(256) void bnred_k(
    const float* __restrict__ bstats, int nrows,
    float* __restrict__ psum)
{
    const int slot = blockIdx.y;
    const int col = blockIdx.x * 8 + (threadIdx.x >> 5);
    const int rl = threadIdx.x & 31;
    const float* bs = bstats + (size_t)slot * nrows * (2 * DIM_);
    float s0 = 0.f, s1 = 0.f, s2 = 0.f, s3 = 0.f;
    int i = rl;
    for (; i + 96 < nrows; i += 128) {
        s0 += bs[(size_t)(i +  0) * (2 * DIM_) + col];
        s1 += bs[(size_t)(i + 32) * (2 * DIM_) + col];
        s2 += bs[(size_t)(i + 64) * (2 * DIM_) + col];
        s3 += bs[(size_t)(i + 96) * (2 * DIM_) + col];
    }
    for (; i < nrows; i += 32) s0 += bs[(size_t)i * (2 * DIM_) + col];
    float s = (s0 + s1) + (s2 + s3);
    #pragma unroll
    for (int off = 16; off; off >>= 1) s += __shfl_down(s, off);
    if (rl == 0) psum[(size_t)slot * 2 * DIM_ + col] = s;
}

// ===========================================================================
// bnfin2_k: finalize fused affine coef {a, b2} from psum. Grid (tc) x 64.
// ===========================================================================
__global__ __launch_bounds__(64) void bnfin2_k(
    const float* __restrict__ psum,
    const float* __restrict__ bng, const float* __restrict__ bnb,
    int t0, int c, float* __restrict__ coef, float inv_n)
{
    const int slot = blockIdx.x;
    const int t = t0 + slot;
    int tid = threadIdx.x;
    if (tid < DIM_) {
        float mean = psum[(size_t)slot * 2 * DIM_ + tid] * inv_n;
        float var  = psum[(size_t)slot * 2 * DIM_ + DIM_ + tid] * inv_n - mean * mean;
        float aa   = bng[((size_t)t * 3 + c) * DIM_ + tid] / sqrtf(var + BN_EPS);
        coef[(size_t)slot * 2 * DIM_ + tid]        = aa;
        coef[(size_t)slot * 2 * DIM_ + DIM_ + tid] = bnb[((size_t)t * 3 + c) * DIM_ + tid] - aa * mean;
    }
}

// ===========================================================================
// pool_k: per-graph mean pool over bf16 z (batch sorted), conv-3 coef.
// ===========================================================================
__global__ __launch_bounds__(288) void pool_k(
    const unsigned short* __restrict__ zh, size_t zstride,
    const float* __restrict__ coef,
    const int* __restrict__ batch, int t0,
    float* __restrict__ emb, int n)
{
    __shared__ int slo, shi;
    __shared__ float sp0[16][19], sp1[16][19];
    const int slot = blockIdx.y;
    const int t = t0 + slot;
    const int* bt = batch + (size_t)t * n;
    const unsigned short* zt = zh + (size_t)slot * zstride;
    const float* ca  = coef + (size_t)slot * 2 * DIM_;
    const float* cb2 = ca + DIM_;

    int g = blockIdx.x;
    int tid = threadIdx.x;
    if (tid == 0) {
        int lo = 0, hi = n;
        while (lo < hi) { int m = (lo + hi) >> 1; if (bt[m] < g) lo = m + 1; else hi = m; }
        slo = lo;
        int lo2 = lo, hi2 = n;
        while (lo2 < hi2) { int m = (lo2 + hi2) >> 1; if (bt[m] < g + 1) lo2 = m + 1; else hi2 = m; }
        shi = lo2;
    }
    __syncthreads();
    int lo = slo, hi = shi;
    int fp = tid % 18, j = tid / 18;
    float acc0 = 0.f, acc1 = 0.f;
    for (int i = lo + j; i < hi; i += 16) {
        unsigned v = *reinterpret_cast<const unsigned*>(zt + (size_t)i * DIM_ + 2 * fp);
        acc0 += bf2f((unsigned short)(v & 0xffff));
        acc1 += bf2f((unsigned short)(v >> 16));
    }
    sp0[j][fp] = acc0;
    sp1[j][fp] = acc1;
    __syncthreads();
    if (tid < DIM_) {
        int f = tid, fpair = f >> 1, hi_ = f & 1;
        float s = 0.f;
        #pragma unroll
        for (int jj = 0; jj < 16; ++jj)
            s += hi_ ? sp1[jj][fpair] : sp0[jj][fpair];
        int cnt = hi - lo;
        float val = 0.f;
        if (cnt > 0) val = ca[f] * (s / (float)cnt) + cb2[f];
        emb[(size_t)g * (T_ * DIM_) + t * DIM_ + f] = val;
    }
}

// ===========================================================================
// head_k: one 64-thread block per graph, layers staged through LDS.
// ===========================================================================
__global__ __launch_bounds__(64) void head_k(
    const float* __restrict__ emb,
    const float* __restrict__ hw1, const float* __restrict__ hb1,
    const float* __restrict__ hw2, const float* __restrict__ hb2,
    const float* __restrict__ hw3, const float* __restrict__ hb3,
    float* __restrict__ out, int ng)
{
    const int EMB = T_ * DIM_;
    int g = blockIdx.x;
    if (g >= ng) return;
    __shared__ float se[EMB], st1[LIN_], st2[OUT_];
    int tid = threadIdx.x;
    for (int i = tid; i < EMB; i += 64) se[i] = emb[(size_t)g * EMB + i];
    __syncthreads();
    if (tid < LIN_) {
        float acc = hb1[tid];
        #pragma unroll
        for (int k = 0; k < EMB; ++k) acc = fmaf(hw1[tid * EMB + k], se[k], acc);
        st1[tid] = fmaxf(acc, 0.f);
    }
    __syncthreads();
    if (tid < OUT_) {
        float acc = hb2[tid];
        #pragma unroll
        for (int k = 0; k < LIN_; ++k) acc = fmaf(hw2[tid * LIN_ + k], st1[k], acc);
        st2[tid] = fmaxf(acc, 0.f);
    }
    __syncthreads();
    if (tid == 0) {
        float acc = hb3[0];
        #pragma unroll
        for (int k = 0; k < OUT_; ++k) acc = fmaf(hw3[k], st2[k], acc);
        out[g] = 1.f / (1.f + expf(-acc));
    }
}

// ===========================================================================
extern "C" void kernel_launch(void* const* d_in, const int* in_sizes, int n_in,
                              void* d_out, int out_size, void* d_ws, size_t ws_size,
                              hipStream_t stream)
{
    const float* x     = (const float*)d_in[0];
    const int*   ei    = (const int*)d_in[1];
    const int*   batch = (const int*)d_in[2];
    const float* wA[3] = {(const float*)d_in[3], (const float*)d_in[7], (const float*)d_in[11]};
    const float* bA[3] = {(const float*)d_in[4], (const float*)d_in[8], (const float*)d_in[12]};
    const float* wB[3] = {(const float*)d_in[5], (const float*)d_in[9], (const float*)d_in[13]};
    const float* bB[3] = {(const float*)d_in[6], (const float*)d_in[10], (const float*)d_in[14]};
    const float* bng = (const float*)d_in[15];
    const float* bnb = (const float*)d_in[16];
    const float* hw1 = (const float*)d_in[17];
    const float* hb1 = (const float*)d_in[18];
    const float* hw2 = (const float*)d_in[19];
    const float* hb2 = (const float*)d_in[20];
    const float* hw3 = (const float*)d_in[21];
    const float* hb3 = (const float*)d_in[22];

    const int N = in_sizes[2] / T_;
    const int E = in_sizes[1] / (2 * T_);
    const int G = out_size;
    const int NB = (N + WMSK_) / 128;
    const int gnq = (N + 63) / 64;            // node_s blocks / stat rows
    const float inv_n = 1.0f / (float)N;
    const int gbin = (E + TILE_ - 1) / TILE_;

    const size_t bufN = (size_t)N * DIM_;
    auto need = [&](int tc) -> size_t {
        size_t f = (size_t)tc * bufN                           // agg fp32
                 + (size_t)tc * gnq * 2 * DIM_                 // bstats
                 + (size_t)tc * 2 * DIM_                       // coef
                 + (size_t)tc * 2 * DIM_                       // psum
                 + (size_t)G * T_ * DIM_;                      // emb
        size_t hs = 2 * (size_t)tc * bufN;                     // zhA + zhB
        size_t ii = (size_t)tc * NB + 2 * (size_t)tc * N + (size_t)tc * NB * CAP_;
        return f * sizeof(float) + hs * sizeof(unsigned short) + ii * sizeof(int);
    };
    const int tcnt = (need(2) <= ws_size) ? 2 : 1;

    char* ws = (char*)d_ws;
    float* agg    = (float*)ws;                               // tc*N*36 fp32
    float* bstats = agg + (size_t)tcnt * bufN;                // tc*gnq*72
    float* coef   = bstats + (size_t)tcnt * gnq * 2 * DIM_;   // tc*72
    float* psum   = coef + (size_t)tcnt * 2 * DIM_;           // tc*72
    float* emb    = psum + (size_t)tcnt * 2 * DIM_;           // G*72
    unsigned short* zhA = (unsigned short*)(emb + (size_t)G * T_ * DIM_);
    unsigned short* zhB = zhA + (size_t)tcnt * bufN;
    int*   bcnt   = (int*)(zhB + (size_t)tcnt * bufN);        // tc*NB
    int*   rp     = bcnt + (size_t)tcnt * NB;                 // tc*N
    int*   deg    = rp + (size_t)tcnt * N;                    // tc*N
    int*   bbuf   = deg + (size_t)tcnt * N;                   // tc*NB*CAP_

    float* outp = (float*)d_out;

    for (int t0 = 0; t0 < T_; t0 += tcnt) {
        const int tc = tcnt;

        hipMemsetAsync(bcnt, 0, (size_t)tc * NB * sizeof(int), stream);
        binsort_k<<<tc * gbin, 256, 0, stream>>>(ei, t0, gbin, bcnt, bbuf, E, NB);
        csrify_k<<<tc * NB, 256, 0, stream>>>(bcnt, bbuf, rp, deg, N, NB);

        // conv1: fp32 gather of x (self folded), MLP -> bf16 zhA
        gather_k<IN_><<<dim3((N + 95) / 96, tc), 576, 0, stream>>>(
                x + (size_t)t0 * N * IN_, (size_t)N * IN_,
                rp, deg, bbuf, agg, (size_t)N * IN_, N);
        node_s<IN_, false><<<dim3(gnq, tc), 256, 0, stream>>>(
                agg, (size_t)N * IN_, deg, nullptr,
                wA[0], bA[0], wB[0], bB[0], t0,
                zhA, bufN, bstats, gnq, N);
        bnred_k<<<dim3(9, tc), 256, 0, stream>>>(bstats, gnq, psum);
        bnfin2_k<<<tc, 64, 0, stream>>>(psum, bng, bnb, t0, 0, coef, inv_n);

        // conv2: bf16 gather zhA -> fp32 agg; MLP -> bf16 zhB
        gather36h_k<<<dim3((N + 63) / 64, tc), 576, 0, stream>>>(
                zhA, bufN, rp, deg, bbuf, agg, bufN, N);
        node_s<DIM_, true><<<dim3(gnq, tc), 256, 0, stream>>>(
                agg, bufN, deg, coef,
                wA[1], bA[1], wB[1], bB[1], t0,
                zhB, bufN, bstats, gnq, N);
        bnred_k<<<dim3(9, tc), 256, 0, stream>>>(bstats, gnq, psum);
        bnfin2_k<<<tc, 64, 0, stream>>>(psum, bng, bnb, t0, 1, coef, inv_n);

        // conv3: bf16 gather zhB -> fp32 agg; MLP -> bf16 zhA
        gather36h_k<<<dim3((N + 63) / 64, tc), 576, 0, stream>>>(
                zhB, bufN, rp, deg, bbuf, agg, bufN, N);
        node_s<DIM_, true><<<dim3(gnq, tc), 256, 0, stream>>>(
                agg, bufN, deg, coef,
                wA[2], bA[2], wB[2], bB[2], t0,
                zhA, bufN, bstats, gnq, N);
        bnred_k<<<dim3(9, tc), 256, 0, stream>>>(bstats, gnq, psum);
        bnfin2_k<<<tc, 64, 0, stream>>>(psum, bng, bnb, t0, 2, coef, inv_n);

        pool_k<<<dim3(G, tc), 288, 0, stream>>>(zhA, bufN, coef, batch, t0, emb, N);
    }
    head_k<<<G, 64, 0, stream>>>(emb, hw1, hb1, hw2, hb2, hw3, hb3, outp, G);
}